// Round 4
// baseline (212.784 us; speedup 1.0000x reference)
//
#include <hip/hip_runtime.h>
#include <hip/hip_bf16.h>
#include <math.h>

// ---------------------------------------------------------------------------
// AdderNet LeNet forward. R3: occupancy/latency round —
//  * adder2: 4-wide quads + c-split-by-2 (shfl_xor combine): 3200 waves.
//  * adder1: 8-wide third-rows: 2880 waves.
//  * BN partial sums fused into adder epilogues (LDS channel atomics ->
//    global atomics); bn_partial kernels deleted.
//  * fc1: block-per-j, 128b x 2 k-halves, coalesced featT, uniform w rows.
// ---------------------------------------------------------------------------

#define B_N 128
#define EPSBN 1e-5f

// ---- adder1 + BN1 partials: x[128,1,28,28], w[20,1,5,5] -> h[128,20,24,24] -
// thread = (b,o,oh,owc in {0,1,2}) computing an 8-wide chunk of the ow row.
__global__ __launch_bounds__(256) void adder1_bn_kernel(
    const float* __restrict__ x, const float* __restrict__ w1,
    float* __restrict__ out, float* __restrict__ sums) {  // sums[2*20]
  __shared__ float csum[40];
  if (threadIdx.x < 40) csum[threadIdx.x] = 0.f;
  __syncthreads();

  int idx = blockIdx.x * 256 + threadIdx.x;   // 184320 = 720*256
  int owc = idx % 3; int t = idx / 3;
  int oh  = t % 24;  t /= 24;
  int o   = t % 20;  int b = t / 20;
  const float* xb = x + b * 784;
  const float* wb = w1 + o * 25;
  float acc[8];
#pragma unroll
  for (int i = 0; i < 8; ++i) acc[i] = 0.f;
#pragma unroll
  for (int kh = 0; kh < 5; ++kh) {
    // 12 input floats starting at (oh+kh)*28 + owc*8 (4-float aligned)
    float xr[12];
    const float4* xp = (const float4*)(xb + (oh + kh) * 28 + owc * 8);
#pragma unroll
    for (int i = 0; i < 3; ++i) {
      float4 v = xp[i];
      xr[4*i] = v.x; xr[4*i+1] = v.y; xr[4*i+2] = v.z; xr[4*i+3] = v.w;
    }
    float wr[5];
#pragma unroll
    for (int i = 0; i < 5; ++i) wr[i] = wb[kh * 5 + i];
#pragma unroll
    for (int ow = 0; ow < 8; ++ow)
#pragma unroll
      for (int kw = 0; kw < 5; ++kw)
        acc[ow] += fabsf(xr[ow + kw] - wr[kw]);
  }
  float* op = out + (((size_t)b * 20 + o) * 24 + oh) * 24 + owc * 8;
  float4 s0 = { -acc[0], -acc[1], -acc[2], -acc[3] };
  float4 s1 = { -acc[4], -acc[5], -acc[6], -acc[7] };
  *(float4*)(op)     = s0;
  *(float4*)(op + 4) = s1;

  // BN1 partials over pre-BN values v = -acc (v^2 == acc^2)
  float s = 0.f, s2 = 0.f;
#pragma unroll
  for (int i = 0; i < 8; ++i) { s -= acc[i]; s2 += acc[i] * acc[i]; }
  atomicAdd(&csum[o * 2],     s);
  atomicAdd(&csum[o * 2 + 1], s2);
  __syncthreads();
  if (threadIdx.x < 40) atomicAdd(&sums[threadIdx.x], csum[threadIdx.x]);
}

// ---- BN finalize + apply + 2x2 maxpool (normal layout out) -----------------
__global__ __launch_bounds__(256) void bn_pool_kernel(
    const float* __restrict__ h, const float* __restrict__ sums,
    const float* __restrict__ gamma, const float* __restrict__ beta,
    float* __restrict__ out, int C, int Hin, int Hout, float inv_n) {
  int idx = blockIdx.x * 256 + threadIdx.x;
  int pw = idx % Hout; int t = idx / Hout;
  int ph = t % Hout;   t /= Hout;
  int c  = t % C;      int b = t / C;
  float sm   = sums[2 * c];
  float s2   = sums[2 * c + 1];
  float mean = sm * inv_n;
  float var  = s2 * inv_n - mean * mean;
  float sc   = gamma[c] * rsqrtf(var + EPSBN);
  float bi   = beta[c] - mean * sc;
  const float* hp = h + ((b * C + c) * Hin + 2 * ph) * Hin + 2 * pw;
  float v0 = fmaf(sc, hp[0],       bi);
  float v1 = fmaf(sc, hp[1],       bi);
  float v2 = fmaf(sc, hp[Hin],     bi);
  float v3 = fmaf(sc, hp[Hin + 1], bi);
  out[idx] = fmaxf(fmaxf(v0, v1), fmaxf(v2, v3));
}

// ---- BN finalize + apply + 2x2 maxpool, TRANSPOSED out: featT[k][b] --------
__global__ __launch_bounds__(256) void bn_pool_t_kernel(
    const float* __restrict__ h, const float* __restrict__ sums,
    const float* __restrict__ gamma, const float* __restrict__ beta,
    float* __restrict__ outT, float inv_n) {   // h:[128,50,8,8] -> outT[800][128]
  int idx = blockIdx.x * 256 + threadIdx.x;    // 102400 = 400*256
  int pw = idx % 4; int t = idx / 4;
  int ph = t % 4;   t /= 4;
  int c  = t % 50;  int b = t / 50;
  float sm   = sums[2 * c];
  float s2   = sums[2 * c + 1];
  float mean = sm * inv_n;
  float var  = s2 * inv_n - mean * mean;
  float sc   = gamma[c] * rsqrtf(var + EPSBN);
  float bi   = beta[c] - mean * sc;
  const float* hp = h + ((b * 50 + c) * 8 + 2 * ph) * 8 + 2 * pw;
  float v0 = fmaf(sc, hp[0], bi);
  float v1 = fmaf(sc, hp[1], bi);
  float v2 = fmaf(sc, hp[8], bi);
  float v3 = fmaf(sc, hp[9], bi);
  int k = (c * 16 + ph * 4 + pw);
  outT[k * 128 + b] = fmaxf(fmaxf(v0, v1), fmaxf(v2, v3));
}

// ---- adder2 + BN2 partials: h[128,20,12,12], w[50,20,5,5] -> [128,50,8,8] --
// thread = (b,o,oh,owq,chalf): 4-wide output quad, 10 channels; c-halves
// combined via shfl_xor(1); even lane stores float4 + accumulates stats.
__global__ __launch_bounds__(256) void adder2_bn_kernel(
    const float* __restrict__ h, const float* __restrict__ w2,
    float* __restrict__ out, float* __restrict__ sums) {  // sums[2*50]
  __shared__ float csum[100];
  if (threadIdx.x < 100) csum[threadIdx.x] = 0.f;
  __syncthreads();

  int idx = blockIdx.x * 256 + threadIdx.x;   // 204800 = 800*256
  int chalf = idx & 1;
  int owq   = (idx >> 1) & 1;
  int oh    = (idx >> 2) & 7;
  int o     = (idx >> 5) % 50;
  int b     = idx / 1600;
  const float* hb = h + (size_t)b * (20 * 144);
  const float* wb = w2 + o * 500;
  float acc[4];
#pragma unroll
  for (int i = 0; i < 4; ++i) acc[i] = 0.f;
  for (int c = chalf * 10; c < chalf * 10 + 10; ++c) {
    const float* hc = hb + c * 144;
    const float* wc = wb + c * 25;
#pragma unroll
    for (int kh = 0; kh < 5; ++kh) {
      // 8 input floats starting at (oh+kh)*12 + owq*4 (4-float aligned)
      float hr[8];
      const float4* hp = (const float4*)(hc + (oh + kh) * 12 + owq * 4);
#pragma unroll
      for (int i = 0; i < 2; ++i) {
        float4 v = hp[i];
        hr[4*i] = v.x; hr[4*i+1] = v.y; hr[4*i+2] = v.z; hr[4*i+3] = v.w;
      }
      float wr[5];
#pragma unroll
      for (int i = 0; i < 5; ++i) wr[i] = wc[kh * 5 + i];
#pragma unroll
      for (int ow = 0; ow < 4; ++ow)
#pragma unroll
        for (int kw = 0; kw < 5; ++kw)
          acc[ow] += fabsf(hr[ow + kw] - wr[kw]);
    }
  }
  // combine the two c-halves (partner lane differs only in bit0 == chalf)
#pragma unroll
  for (int i = 0; i < 4; ++i) acc[i] += __shfl_xor(acc[i], 1);

  if (chalf == 0) {
    float4 st = { -acc[0], -acc[1], -acc[2], -acc[3] };
    *(float4*)(out + (((size_t)b * 50 + o) * 8 + oh) * 8 + owq * 4) = st;
    float s = 0.f, s2 = 0.f;
#pragma unroll
    for (int i = 0; i < 4; ++i) { s -= acc[i]; s2 += acc[i] * acc[i]; }
    atomicAdd(&csum[o * 2],     s);
    atomicAdd(&csum[o * 2 + 1], s2);
  }
  __syncthreads();
  if (threadIdx.x < 100) atomicAdd(&sums[threadIdx.x], csum[threadIdx.x]);
}

// ---- fc1 + relu: featT[800][128] x w[500,800] -> hid[128][512] -------------
// block = j (500 blocks); 256 threads = 128 b x 2 k-halves; featT coalesced,
// w row wave-uniform; 4 independent accumulators; LDS pair combine.
__global__ __launch_bounds__(256) void fc1_kernel(
    const float* __restrict__ featT, const float* __restrict__ w1,
    const float* __restrict__ b1, float* __restrict__ hid) {
  const int j = blockIdx.x;
  const int b = threadIdx.x & 127;
  const int khalf = threadIdx.x >> 7;
  const float* wr = w1 + j * 800;
  const float* fb = featT + b;
  float a0 = 0.f, a1 = 0.f, a2 = 0.f, a3 = 0.f;
  int k0 = khalf * 400;
  for (int k = k0; k < k0 + 400; k += 4) {
    float4 w4 = *(const float4*)(wr + k);   // wave-uniform
    a0 = fmaf(fb[(k    ) * 128], w4.x, a0);
    a1 = fmaf(fb[(k + 1) * 128], w4.y, a1);
    a2 = fmaf(fb[(k + 2) * 128], w4.z, a2);
    a3 = fmaf(fb[(k + 3) * 128], w4.w, a3);
  }
  __shared__ float part[256];
  part[threadIdx.x] = (a0 + a1) + (a2 + a3);
  __syncthreads();
  if (threadIdx.x < 128)
    hid[b * 512 + j] =
        fmaxf(b1[j] + part[threadIdx.x] + part[threadIdx.x + 128], 0.f);
}

// ---- fc2 + bias + softmax: hid[128][512] x w[10,500] -> out[128][10] -------
__global__ __launch_bounds__(64) void fc2_softmax_kernel(
    const float* __restrict__ hid, const float* __restrict__ w2,
    const float* __restrict__ b2, float* __restrict__ out) {
  const int b = blockIdx.x, lane = threadIdx.x;
  const float* hb = hid + b * 512;
  __shared__ float logit[16];
  for (int j = 0; j < 10; ++j) {
    const float* wr = w2 + j * 500;
    float acc = 0.f;
    for (int k = lane; k < 500; k += 64) acc += hb[k] * wr[k];
#pragma unroll
    for (int off = 32; off > 0; off >>= 1) acc += __shfl_down(acc, off);
    if (lane == 0) logit[j] = acc + b2[j];
  }
  __syncthreads();
  if (lane == 0) {
    float m = logit[0];
    for (int j = 1; j < 10; ++j) m = fmaxf(m, logit[j]);
    float s = 0.f, e[10];
    for (int j = 0; j < 10; ++j) { e[j] = __expf(logit[j] - m); s += e[j]; }
    float inv = 1.f / s;
    for (int j = 0; j < 10; ++j) out[b * 10 + j] = e[j] * inv;
  }
}

extern "C" void kernel_launch(void* const* d_in, const int* in_sizes, int n_in,
                              void* d_out, int out_size, void* d_ws, size_t ws_size,
                              hipStream_t stream) {
  const float* x   = (const float*)d_in[0];   // [128,1,28,28]
  const float* w1  = (const float*)d_in[1];   // [20,1,5,5]
  const float* g1  = (const float*)d_in[2];   // [20]
  const float* be1 = (const float*)d_in[3];   // [20]
  const float* w2  = (const float*)d_in[4];   // [50,20,5,5]
  const float* g2  = (const float*)d_in[5];   // [50]
  const float* be2 = (const float*)d_in[6];   // [50]
  const float* fw1 = (const float*)d_in[7];   // [500,800]
  const float* fb1 = (const float*)d_in[8];   // [500]
  const float* fw2 = (const float*)d_in[9];   // [10,500]
  const float* fb2 = (const float*)d_in[10];  // [10]
  float* out = (float*)d_out;

  // workspace layout (floats); regions inside h1 reused once h1 is dead.
  float* ws    = (float*)d_ws;
  float* h1    = ws;               // [0, 1474560)        128*20*24*24
  float* h1p   = ws + 1474560;     // [1474560, 1843200)  128*20*12*12
  float* h2    = ws;               // reuse: [0, 409600)  128*50*8*8
  float* featT = ws + 409600;      // [409600, 512000)    800*128 (dead h1)
  float* hid   = ws + 512000;      // [512000, 577536)    128*512 (dead h1)
  float* sums1 = ws + 1843200;     // [2*20]
  float* sums2 = sums1 + 40;       // [2*50]

  hipMemsetAsync(sums1, 0, 140 * sizeof(float), stream);

  adder1_bn_kernel<<<720, 256, 0, stream>>>(x, w1, h1, sums1);
  bn_pool_kernel<<<1440, 256, 0, stream>>>(h1, sums1, g1, be1, h1p, 20, 24, 12,
                                           1.f / (B_N * 576));
  adder2_bn_kernel<<<800, 256, 0, stream>>>(h1p, w2, h2, sums2);
  bn_pool_t_kernel<<<400, 256, 0, stream>>>(h2, sums2, g2, be2, featT,
                                            1.f / (B_N * 64));
  fc1_kernel<<<500, 256, 0, stream>>>(featT, fw1, fb1, hid);
  fc2_softmax_kernel<<<128, 64, 0, stream>>>(hid, fw2, fb2, out);
}

// Round 5
// 191.377 us; speedup vs baseline: 1.1119x; 1.1119x over previous
//
#include <hip/hip_runtime.h>
#include <hip/hip_bf16.h>
#include <math.h>

// ---------------------------------------------------------------------------
// AdderNet LeNet forward. R4: R3's fused-BN global atomics serialized ~800
// deep per address (FETCH +3.2MB of atomic line traffic). R5: 16-copy
// accumulators (block -> copy blockIdx&15) + skip exactly-zero entries;
// bn_pool finalize sums the copies. Adder mappings kept from R4.
// ---------------------------------------------------------------------------

#define B_N 128
#define EPSBN 1e-5f
#define NCOPY 16

// ---- adder1 + BN1 partials: x[128,1,28,28], w[20,1,5,5] -> h[128,20,24,24] -
// thread = (b,o,oh,owc in {0,1,2}) computing an 8-wide chunk of the ow row.
__global__ __launch_bounds__(256) void adder1_bn_kernel(
    const float* __restrict__ x, const float* __restrict__ w1,
    float* __restrict__ out, float* __restrict__ sums) {  // sums[NCOPY*40]
  __shared__ float csum[40];
  if (threadIdx.x < 40) csum[threadIdx.x] = 0.f;
  __syncthreads();

  int idx = blockIdx.x * 256 + threadIdx.x;   // 184320 = 720*256
  int owc = idx % 3; int t = idx / 3;
  int oh  = t % 24;  t /= 24;
  int o   = t % 20;  int b = t / 20;
  const float* xb = x + b * 784;
  const float* wb = w1 + o * 25;
  float acc[8];
#pragma unroll
  for (int i = 0; i < 8; ++i) acc[i] = 0.f;
#pragma unroll
  for (int kh = 0; kh < 5; ++kh) {
    float xr[12];
    const float4* xp = (const float4*)(xb + (oh + kh) * 28 + owc * 8);
#pragma unroll
    for (int i = 0; i < 3; ++i) {
      float4 v = xp[i];
      xr[4*i] = v.x; xr[4*i+1] = v.y; xr[4*i+2] = v.z; xr[4*i+3] = v.w;
    }
    float wr[5];
#pragma unroll
    for (int i = 0; i < 5; ++i) wr[i] = wb[kh * 5 + i];
#pragma unroll
    for (int ow = 0; ow < 8; ++ow)
#pragma unroll
      for (int kw = 0; kw < 5; ++kw)
        acc[ow] += fabsf(xr[ow + kw] - wr[kw]);
  }
  float* op = out + (((size_t)b * 20 + o) * 24 + oh) * 24 + owc * 8;
  float4 s0 = { -acc[0], -acc[1], -acc[2], -acc[3] };
  float4 s1 = { -acc[4], -acc[5], -acc[6], -acc[7] };
  *(float4*)(op)     = s0;
  *(float4*)(op + 4) = s1;

  float s = 0.f, s2 = 0.f;
#pragma unroll
  for (int i = 0; i < 8; ++i) { s -= acc[i]; s2 += acc[i] * acc[i]; }
  atomicAdd(&csum[o * 2],     s);
  atomicAdd(&csum[o * 2 + 1], s2);
  __syncthreads();
  if (threadIdx.x < 40) {
    float v = csum[threadIdx.x];
    if (v != 0.f)   // untouched channel entries are exactly 0 -> skip (no-op)
      atomicAdd(&sums[(blockIdx.x & (NCOPY - 1)) * 40 + threadIdx.x], v);
  }
}

// ---- BN finalize (16-copy sum) + apply + 2x2 maxpool -----------------------
__global__ __launch_bounds__(256) void bn_pool_kernel(
    const float* __restrict__ h, const float* __restrict__ sums, int stride,
    const float* __restrict__ gamma, const float* __restrict__ beta,
    float* __restrict__ out, int C, int Hin, int Hout, float inv_n) {
  int idx = blockIdx.x * 256 + threadIdx.x;
  int pw = idx % Hout; int t = idx / Hout;
  int ph = t % Hout;   t /= Hout;
  int c  = t % C;      int b = t / C;
  float sm = 0.f, s2 = 0.f;
#pragma unroll
  for (int cp = 0; cp < NCOPY; ++cp) {
    sm += sums[cp * stride + 2 * c];
    s2 += sums[cp * stride + 2 * c + 1];
  }
  float mean = sm * inv_n;
  float var  = s2 * inv_n - mean * mean;
  float sc   = gamma[c] * rsqrtf(var + EPSBN);
  float bi   = beta[c] - mean * sc;
  const float* hp = h + ((b * C + c) * Hin + 2 * ph) * Hin + 2 * pw;
  float v0 = fmaf(sc, hp[0],       bi);
  float v1 = fmaf(sc, hp[1],       bi);
  float v2 = fmaf(sc, hp[Hin],     bi);
  float v3 = fmaf(sc, hp[Hin + 1], bi);
  out[idx] = fmaxf(fmaxf(v0, v1), fmaxf(v2, v3));
}

// ---- BN finalize + apply + 2x2 maxpool, TRANSPOSED out: featT[k][b] --------
__global__ __launch_bounds__(256) void bn_pool_t_kernel(
    const float* __restrict__ h, const float* __restrict__ sums,
    const float* __restrict__ gamma, const float* __restrict__ beta,
    float* __restrict__ outT, float inv_n) {   // h:[128,50,8,8] -> outT[800][128]
  int idx = blockIdx.x * 256 + threadIdx.x;    // 102400 = 400*256
  int pw = idx % 4; int t = idx / 4;
  int ph = t % 4;   t /= 4;
  int c  = t % 50;  int b = t / 50;
  float sm = 0.f, s2 = 0.f;
#pragma unroll
  for (int cp = 0; cp < NCOPY; ++cp) {
    sm += sums[cp * 100 + 2 * c];
    s2 += sums[cp * 100 + 2 * c + 1];
  }
  float mean = sm * inv_n;
  float var  = s2 * inv_n - mean * mean;
  float sc   = gamma[c] * rsqrtf(var + EPSBN);
  float bi   = beta[c] - mean * sc;
  const float* hp = h + ((b * 50 + c) * 8 + 2 * ph) * 8 + 2 * pw;
  float v0 = fmaf(sc, hp[0], bi);
  float v1 = fmaf(sc, hp[1], bi);
  float v2 = fmaf(sc, hp[8], bi);
  float v3 = fmaf(sc, hp[9], bi);
  int k = (c * 16 + ph * 4 + pw);
  outT[k * 128 + b] = fmaxf(fmaxf(v0, v1), fmaxf(v2, v3));
}

// ---- adder2 + BN2 partials: h[128,20,12,12], w[50,20,5,5] -> [128,50,8,8] --
// thread = (b,o,oh,owq,chalf): 4-wide output quad, 10 channels; c-halves
// combined via shfl_xor(1); even lane stores float4 + accumulates stats.
__global__ __launch_bounds__(256) void adder2_bn_kernel(
    const float* __restrict__ h, const float* __restrict__ w2,
    float* __restrict__ out, float* __restrict__ sums) {  // sums[NCOPY*100]
  __shared__ float csum[100];
  if (threadIdx.x < 100) csum[threadIdx.x] = 0.f;
  __syncthreads();

  int idx = blockIdx.x * 256 + threadIdx.x;   // 204800 = 800*256
  int chalf = idx & 1;
  int owq   = (idx >> 1) & 1;
  int oh    = (idx >> 2) & 7;
  int o     = (idx >> 5) % 50;
  int b     = idx / 1600;
  const float* hb = h + (size_t)b * (20 * 144);
  const float* wb = w2 + o * 500;
  float acc[4];
#pragma unroll
  for (int i = 0; i < 4; ++i) acc[i] = 0.f;
  for (int c = chalf * 10; c < chalf * 10 + 10; ++c) {
    const float* hc = hb + c * 144;
    const float* wc = wb + c * 25;
#pragma unroll
    for (int kh = 0; kh < 5; ++kh) {
      float hr[8];
      const float4* hp = (const float4*)(hc + (oh + kh) * 12 + owq * 4);
#pragma unroll
      for (int i = 0; i < 2; ++i) {
        float4 v = hp[i];
        hr[4*i] = v.x; hr[4*i+1] = v.y; hr[4*i+2] = v.z; hr[4*i+3] = v.w;
      }
      float wr[5];
#pragma unroll
      for (int i = 0; i < 5; ++i) wr[i] = wc[kh * 5 + i];
#pragma unroll
      for (int ow = 0; ow < 4; ++ow)
#pragma unroll
        for (int kw = 0; kw < 5; ++kw)
          acc[ow] += fabsf(hr[ow + kw] - wr[kw]);
    }
  }
#pragma unroll
  for (int i = 0; i < 4; ++i) acc[i] += __shfl_xor(acc[i], 1);

  if (chalf == 0) {
    float4 st = { -acc[0], -acc[1], -acc[2], -acc[3] };
    *(float4*)(out + (((size_t)b * 50 + o) * 8 + oh) * 8 + owq * 4) = st;
    float s = 0.f, s2 = 0.f;
#pragma unroll
    for (int i = 0; i < 4; ++i) { s -= acc[i]; s2 += acc[i] * acc[i]; }
    atomicAdd(&csum[o * 2],     s);
    atomicAdd(&csum[o * 2 + 1], s2);
  }
  __syncthreads();
  if (threadIdx.x < 100) {
    float v = csum[threadIdx.x];
    if (v != 0.f)   // only ~16 of 100 entries touched per block
      atomicAdd(&sums[(blockIdx.x & (NCOPY - 1)) * 100 + threadIdx.x], v);
  }
}

// ---- fc1 + relu: featT[800][128] x w[500,800] -> hid[128][512] -------------
__global__ __launch_bounds__(256) void fc1_kernel(
    const float* __restrict__ featT, const float* __restrict__ w1,
    const float* __restrict__ b1, float* __restrict__ hid) {
  const int j = blockIdx.x;
  const int b = threadIdx.x & 127;
  const int khalf = threadIdx.x >> 7;
  const float* wr = w1 + j * 800;
  const float* fb = featT + b;
  float a0 = 0.f, a1 = 0.f, a2 = 0.f, a3 = 0.f;
  int k0 = khalf * 400;
  for (int k = k0; k < k0 + 400; k += 4) {
    float4 w4 = *(const float4*)(wr + k);   // wave-uniform
    a0 = fmaf(fb[(k    ) * 128], w4.x, a0);
    a1 = fmaf(fb[(k + 1) * 128], w4.y, a1);
    a2 = fmaf(fb[(k + 2) * 128], w4.z, a2);
    a3 = fmaf(fb[(k + 3) * 128], w4.w, a3);
  }
  __shared__ float part[256];
  part[threadIdx.x] = (a0 + a1) + (a2 + a3);
  __syncthreads();
  if (threadIdx.x < 128)
    hid[b * 512 + j] =
        fmaxf(b1[j] + part[threadIdx.x] + part[threadIdx.x + 128], 0.f);
}

// ---- fc2 + bias + softmax: hid[128][512] x w[10,500] -> out[128][10] -------
__global__ __launch_bounds__(64) void fc2_softmax_kernel(
    const float* __restrict__ hid, const float* __restrict__ w2,
    const float* __restrict__ b2, float* __restrict__ out) {
  const int b = blockIdx.x, lane = threadIdx.x;
  const float* hb = hid + b * 512;
  __shared__ float logit[16];
  for (int j = 0; j < 10; ++j) {
    const float* wr = w2 + j * 500;
    float acc = 0.f;
    for (int k = lane; k < 500; k += 64) acc += hb[k] * wr[k];
#pragma unroll
    for (int off = 32; off > 0; off >>= 1) acc += __shfl_down(acc, off);
    if (lane == 0) logit[j] = acc + b2[j];
  }
  __syncthreads();
  if (lane == 0) {
    float m = logit[0];
    for (int j = 1; j < 10; ++j) m = fmaxf(m, logit[j]);
    float s = 0.f, e[10];
    for (int j = 0; j < 10; ++j) { e[j] = __expf(logit[j] - m); s += e[j]; }
    float inv = 1.f / s;
    for (int j = 0; j < 10; ++j) out[b * 10 + j] = e[j] * inv;
  }
}

extern "C" void kernel_launch(void* const* d_in, const int* in_sizes, int n_in,
                              void* d_out, int out_size, void* d_ws, size_t ws_size,
                              hipStream_t stream) {
  const float* x   = (const float*)d_in[0];   // [128,1,28,28]
  const float* w1  = (const float*)d_in[1];   // [20,1,5,5]
  const float* g1  = (const float*)d_in[2];   // [20]
  const float* be1 = (const float*)d_in[3];   // [20]
  const float* w2  = (const float*)d_in[4];   // [50,20,5,5]
  const float* g2  = (const float*)d_in[5];   // [50]
  const float* be2 = (const float*)d_in[6];   // [50]
  const float* fw1 = (const float*)d_in[7];   // [500,800]
  const float* fb1 = (const float*)d_in[8];   // [500]
  const float* fw2 = (const float*)d_in[9];   // [10,500]
  const float* fb2 = (const float*)d_in[10];  // [10]
  float* out = (float*)d_out;

  // workspace layout (floats); regions inside h1 reused once h1 is dead.
  float* ws    = (float*)d_ws;
  float* h1    = ws;               // [0, 1474560)        128*20*24*24
  float* h1p   = ws + 1474560;     // [1474560, 1843200)  128*20*12*12
  float* h2    = ws;               // reuse: [0, 409600)  128*50*8*8
  float* featT = ws + 409600;      // [409600, 512000)    800*128 (dead h1)
  float* hid   = ws + 512000;      // [512000, 577536)    128*512 (dead h1)
  float* sums1 = ws + 1843200;     // NCOPY*40 floats
  float* sums2 = sums1 + NCOPY*40; // NCOPY*100 floats

  hipMemsetAsync(sums1, 0, NCOPY * 140 * sizeof(float), stream);

  adder1_bn_kernel<<<720, 256, 0, stream>>>(x, w1, h1, sums1);
  bn_pool_kernel<<<1440, 256, 0, stream>>>(h1, sums1, 40, g1, be1, h1p,
                                           20, 24, 12, 1.f / (B_N * 576));
  adder2_bn_kernel<<<800, 256, 0, stream>>>(h1p, w2, h2, sums2);
  bn_pool_t_kernel<<<400, 256, 0, stream>>>(h2, sums2, g2, be2, featT,
                                            1.f / (B_N * 64));
  fc1_kernel<<<500, 256, 0, stream>>>(featT, fw1, fb1, hid);
  fc2_softmax_kernel<<<128, 64, 0, stream>>>(hid, fw2, fb2, out);
}

// Round 6
// 162.366 us; speedup vs baseline: 1.3105x; 1.1787x over previous
//
#include <hip/hip_runtime.h>
#include <hip/hip_bf16.h>
#include <math.h>

// ---------------------------------------------------------------------------
// AdderNet LeNet forward. R6: adder2 was L1-thrashing (50x logical re-read of
// h1p slices + stride-500 w2 rows; VALUBusy 20%). Now: block=(b,oh-quarter)
// stages its 6 h rows x 20c (5.76KB) into LDS once; w2 pre-transposed to
// w2t[c][k][o] so w loads are lane-contiguous/broadcast. 16-copy BN-stat
// accumulators kept from R5.
// ---------------------------------------------------------------------------

#define B_N 128
#define EPSBN 1e-5f
#define NCOPY 16

// ---- adder1 + BN1 partials: x[128,1,28,28], w[20,1,5,5] -> h[128,20,24,24] -
// thread = (b,o,oh,owc in {0,1,2}) computing an 8-wide chunk of the ow row.
__global__ __launch_bounds__(256) void adder1_bn_kernel(
    const float* __restrict__ x, const float* __restrict__ w1,
    float* __restrict__ out, float* __restrict__ sums) {  // sums[NCOPY*40]
  __shared__ float csum[40];
  if (threadIdx.x < 40) csum[threadIdx.x] = 0.f;
  __syncthreads();

  int idx = blockIdx.x * 256 + threadIdx.x;   // 184320 = 720*256
  int owc = idx % 3; int t = idx / 3;
  int oh  = t % 24;  t /= 24;
  int o   = t % 20;  int b = t / 20;
  const float* xb = x + b * 784;
  const float* wb = w1 + o * 25;
  float acc[8];
#pragma unroll
  for (int i = 0; i < 8; ++i) acc[i] = 0.f;
#pragma unroll
  for (int kh = 0; kh < 5; ++kh) {
    float xr[12];
    const float4* xp = (const float4*)(xb + (oh + kh) * 28 + owc * 8);
#pragma unroll
    for (int i = 0; i < 3; ++i) {
      float4 v = xp[i];
      xr[4*i] = v.x; xr[4*i+1] = v.y; xr[4*i+2] = v.z; xr[4*i+3] = v.w;
    }
    float wr[5];
#pragma unroll
    for (int i = 0; i < 5; ++i) wr[i] = wb[kh * 5 + i];
#pragma unroll
    for (int ow = 0; ow < 8; ++ow)
#pragma unroll
      for (int kw = 0; kw < 5; ++kw)
        acc[ow] += fabsf(xr[ow + kw] - wr[kw]);
  }
  float* op = out + (((size_t)b * 20 + o) * 24 + oh) * 24 + owc * 8;
  float4 s0 = { -acc[0], -acc[1], -acc[2], -acc[3] };
  float4 s1 = { -acc[4], -acc[5], -acc[6], -acc[7] };
  *(float4*)(op)     = s0;
  *(float4*)(op + 4) = s1;

  float s = 0.f, s2 = 0.f;
#pragma unroll
  for (int i = 0; i < 8; ++i) { s -= acc[i]; s2 += acc[i] * acc[i]; }
  atomicAdd(&csum[o * 2],     s);
  atomicAdd(&csum[o * 2 + 1], s2);
  __syncthreads();
  if (threadIdx.x < 40) {
    float v = csum[threadIdx.x];
    if (v != 0.f)
      atomicAdd(&sums[(blockIdx.x & (NCOPY - 1)) * 40 + threadIdx.x], v);
  }
}

// ---- BN finalize (16-copy sum) + apply + 2x2 maxpool -----------------------
__global__ __launch_bounds__(256) void bn_pool_kernel(
    const float* __restrict__ h, const float* __restrict__ sums, int stride,
    const float* __restrict__ gamma, const float* __restrict__ beta,
    float* __restrict__ out, int C, int Hin, int Hout, float inv_n) {
  int idx = blockIdx.x * 256 + threadIdx.x;
  int pw = idx % Hout; int t = idx / Hout;
  int ph = t % Hout;   t /= Hout;
  int c  = t % C;      int b = t / C;
  float sm = 0.f, s2 = 0.f;
#pragma unroll
  for (int cp = 0; cp < NCOPY; ++cp) {
    sm += sums[cp * stride + 2 * c];
    s2 += sums[cp * stride + 2 * c + 1];
  }
  float mean = sm * inv_n;
  float var  = s2 * inv_n - mean * mean;
  float sc   = gamma[c] * rsqrtf(var + EPSBN);
  float bi   = beta[c] - mean * sc;
  const float* hp = h + ((b * C + c) * Hin + 2 * ph) * Hin + 2 * pw;
  float v0 = fmaf(sc, hp[0],       bi);
  float v1 = fmaf(sc, hp[1],       bi);
  float v2 = fmaf(sc, hp[Hin],     bi);
  float v3 = fmaf(sc, hp[Hin + 1], bi);
  out[idx] = fmaxf(fmaxf(v0, v1), fmaxf(v2, v3));
}

// ---- BN finalize + apply + 2x2 maxpool, TRANSPOSED out: featT[k][b] --------
__global__ __launch_bounds__(256) void bn_pool_t_kernel(
    const float* __restrict__ h, const float* __restrict__ sums,
    const float* __restrict__ gamma, const float* __restrict__ beta,
    float* __restrict__ outT, float inv_n) {   // h:[128,50,8,8] -> outT[800][128]
  int idx = blockIdx.x * 256 + threadIdx.x;    // 102400 = 400*256
  int pw = idx % 4; int t = idx / 4;
  int ph = t % 4;   t /= 4;
  int c  = t % 50;  int b = t / 50;
  float sm = 0.f, s2 = 0.f;
#pragma unroll
  for (int cp = 0; cp < NCOPY; ++cp) {
    sm += sums[cp * 100 + 2 * c];
    s2 += sums[cp * 100 + 2 * c + 1];
  }
  float mean = sm * inv_n;
  float var  = s2 * inv_n - mean * mean;
  float sc   = gamma[c] * rsqrtf(var + EPSBN);
  float bi   = beta[c] - mean * sc;
  const float* hp = h + ((b * 50 + c) * 8 + 2 * ph) * 8 + 2 * pw;
  float v0 = fmaf(sc, hp[0], bi);
  float v1 = fmaf(sc, hp[1], bi);
  float v2 = fmaf(sc, hp[8], bi);
  float v3 = fmaf(sc, hp[9], bi);
  int k = (c * 16 + ph * 4 + pw);
  outT[k * 128 + b] = fmaxf(fmaxf(v0, v1), fmaxf(v2, v3));
}

// ---- w2 transpose: w2[50,20,5,5] -> w2t[c][k][o] = [20][25][64] ------------
__global__ __launch_bounds__(256) void w2t_prep_kernel(
    const float* __restrict__ w2, float* __restrict__ w2t) {
  int idx = blockIdx.x * 256 + threadIdx.x;   // 32000 = 125*256
  int o = idx & 63;
  int t = idx >> 6;        // c*25 + k
  int k = t % 25, c = t / 25;
  w2t[idx] = (o < 50) ? w2[o * 500 + c * 25 + k] : 0.f;
}

// ---- adder2 + BN2 partials, LDS-staged: h[128,20,12,12] -> [128,50,8,8] ----
// block = (b, oq): stages h rows [2oq, 2oq+6) x 20c into LDS; thread =
// (o=tid>>2, ohl=(tid&3)>>1, owh=tid&1) computes a 4-wide quad over 20c.
__global__ __launch_bounds__(256) void adder2_bn_kernel(
    const float* __restrict__ h, const float* __restrict__ w2t,
    float* __restrict__ out, float* __restrict__ sums) {  // sums[NCOPY*100]
  __shared__ float lh[1440];    // [c][6 rows][12]
  __shared__ float csum[100];
  if (threadIdx.x < 100) csum[threadIdx.x] = 0.f;

  const int oq = blockIdx.x & 3;
  const int b  = blockIdx.x >> 2;   // 512 blocks = 128 b * 4 oq

  // stage: 720 float2 = rows [2oq,2oq+6) of each of 20 channels
  {
    const float* hb = h + (size_t)b * 2880 + 2 * oq * 12;
    float2* dst = (float2*)lh;
    for (int j = threadIdx.x; j < 720; j += 256) {
      int c = j / 36, rem = j - c * 36;              // 36 float2 per channel
      dst[j] = ((const float2*)(hb + c * 144))[rem];
    }
  }
  __syncthreads();

  const int o   = threadIdx.x >> 2;   // 0..63 (active < 50)
  const int q   = threadIdx.x & 3;
  const int ohl = q >> 1;             // local oh 0/1
  const int owh = q & 1;              // ow half

  if (o < 50) {
    float acc[4];
#pragma unroll
    for (int i = 0; i < 4; ++i) acc[i] = 0.f;
    for (int c = 0; c < 20; ++c) {
      const float* lc = lh + c * 72 + owh * 4;
      const float* wc = w2t + c * 1600 + o;
#pragma unroll
      for (int kh = 0; kh < 5; ++kh) {
        float hr[8];
        const float* lp = lc + (ohl + kh) * 12;      // 16B aligned
        *(float4*)(hr)     = *(const float4*)(lp);
        *(float4*)(hr + 4) = *(const float4*)(lp + 4);
        float wr[5];
#pragma unroll
        for (int i = 0; i < 5; ++i) wr[i] = wc[(kh * 5 + i) * 64];
#pragma unroll
        for (int ow = 0; ow < 4; ++ow)
#pragma unroll
          for (int kw = 0; kw < 5; ++kw)
            acc[ow] += fabsf(hr[ow + kw] - wr[kw]);
      }
    }
    const int oh = 2 * oq + ohl;
    float4 st = { -acc[0], -acc[1], -acc[2], -acc[3] };
    *(float4*)(out + (((size_t)b * 50 + o) * 8 + oh) * 8 + owh * 4) = st;
    float s = 0.f, s2 = 0.f;
#pragma unroll
    for (int i = 0; i < 4; ++i) { s -= acc[i]; s2 += acc[i] * acc[i]; }
    atomicAdd(&csum[o * 2],     s);
    atomicAdd(&csum[o * 2 + 1], s2);
  }
  __syncthreads();
  if (threadIdx.x < 100)
    atomicAdd(&sums[(blockIdx.x & (NCOPY - 1)) * 100 + threadIdx.x],
              csum[threadIdx.x]);
}

// ---- fc1 + relu: featT[800][128] x w[500,800] -> hid[128][512] -------------
__global__ __launch_bounds__(256) void fc1_kernel(
    const float* __restrict__ featT, const float* __restrict__ w1,
    const float* __restrict__ b1, float* __restrict__ hid) {
  const int j = blockIdx.x;
  const int b = threadIdx.x & 127;
  const int khalf = threadIdx.x >> 7;
  const float* wr = w1 + j * 800;
  const float* fb = featT + b;
  float a0 = 0.f, a1 = 0.f, a2 = 0.f, a3 = 0.f;
  int k0 = khalf * 400;
  for (int k = k0; k < k0 + 400; k += 4) {
    float4 w4 = *(const float4*)(wr + k);   // wave-uniform
    a0 = fmaf(fb[(k    ) * 128], w4.x, a0);
    a1 = fmaf(fb[(k + 1) * 128], w4.y, a1);
    a2 = fmaf(fb[(k + 2) * 128], w4.z, a2);
    a3 = fmaf(fb[(k + 3) * 128], w4.w, a3);
  }
  __shared__ float part[256];
  part[threadIdx.x] = (a0 + a1) + (a2 + a3);
  __syncthreads();
  if (threadIdx.x < 128)
    hid[b * 512 + j] =
        fmaxf(b1[j] + part[threadIdx.x] + part[threadIdx.x + 128], 0.f);
}

// ---- fc2 + bias + softmax: hid[128][512] x w[10,500] -> out[128][10] -------
__global__ __launch_bounds__(64) void fc2_softmax_kernel(
    const float* __restrict__ hid, const float* __restrict__ w2,
    const float* __restrict__ b2, float* __restrict__ out) {
  const int b = blockIdx.x, lane = threadIdx.x;
  const float* hb = hid + b * 512;
  __shared__ float logit[16];
  for (int j = 0; j < 10; ++j) {
    const float* wr = w2 + j * 500;
    float acc = 0.f;
    for (int k = lane; k < 500; k += 64) acc += hb[k] * wr[k];
#pragma unroll
    for (int off = 32; off > 0; off >>= 1) acc += __shfl_down(acc, off);
    if (lane == 0) logit[j] = acc + b2[j];
  }
  __syncthreads();
  if (lane == 0) {
    float m = logit[0];
    for (int j = 1; j < 10; ++j) m = fmaxf(m, logit[j]);
    float s = 0.f, e[10];
    for (int j = 0; j < 10; ++j) { e[j] = __expf(logit[j] - m); s += e[j]; }
    float inv = 1.f / s;
    for (int j = 0; j < 10; ++j) out[b * 10 + j] = e[j] * inv;
  }
}

extern "C" void kernel_launch(void* const* d_in, const int* in_sizes, int n_in,
                              void* d_out, int out_size, void* d_ws, size_t ws_size,
                              hipStream_t stream) {
  const float* x   = (const float*)d_in[0];   // [128,1,28,28]
  const float* w1  = (const float*)d_in[1];   // [20,1,5,5]
  const float* g1  = (const float*)d_in[2];   // [20]
  const float* be1 = (const float*)d_in[3];   // [20]
  const float* w2  = (const float*)d_in[4];   // [50,20,5,5]
  const float* g2  = (const float*)d_in[5];   // [50]
  const float* be2 = (const float*)d_in[6];   // [50]
  const float* fw1 = (const float*)d_in[7];   // [500,800]
  const float* fb1 = (const float*)d_in[8];   // [500]
  const float* fw2 = (const float*)d_in[9];   // [10,500]
  const float* fb2 = (const float*)d_in[10];  // [10]
  float* out = (float*)d_out;

  // workspace layout (floats); regions inside h1 reused once h1 is dead.
  float* ws    = (float*)d_ws;
  float* h1    = ws;               // [0, 1474560)        128*20*24*24
  float* h1p   = ws + 1474560;     // [1474560, 1843200)  128*20*12*12
  float* h2    = ws;               // reuse: [0, 409600)  128*50*8*8
  float* featT = ws + 409600;      // [409600, 512000)    800*128 (dead h1)
  float* hid   = ws + 512000;      // [512000, 577536)    128*512 (dead h1)
  float* w2t   = ws + 600000;      // [600000, 632000)    20*25*64 (dead h1)
  float* sums1 = ws + 1843200;     // NCOPY*40 floats
  float* sums2 = sums1 + NCOPY*40; // NCOPY*100 floats

  hipMemsetAsync(sums1, 0, NCOPY * 140 * sizeof(float), stream);

  adder1_bn_kernel<<<720, 256, 0, stream>>>(x, w1, h1, sums1);
  bn_pool_kernel<<<1440, 256, 0, stream>>>(h1, sums1, 40, g1, be1, h1p,
                                           20, 24, 12, 1.f / (B_N * 576));
  w2t_prep_kernel<<<125, 256, 0, stream>>>(w2, w2t);
  adder2_bn_kernel<<<512, 256, 0, stream>>>(h1p, w2t, h2, sums2);
  bn_pool_t_kernel<<<400, 256, 0, stream>>>(h2, sums2, g2, be2, featT,
                                            1.f / (B_N * 64));
  fc1_kernel<<<500, 256, 0, stream>>>(featT, fw1, fb1, hid);
  fc2_softmax_kernel<<<128, 64, 0, stream>>>(hid, fw2, fb2, out);
}

// Round 9
// 147.520 us; speedup vs baseline: 1.4424x; 1.1006x over previous
//
#include <hip/hip_runtime.h>
#include <hip/hip_bf16.h>
#include <math.h>

// ---------------------------------------------------------------------------
// AdderNet LeNet forward. R9: back to the PROVEN R6 multi-kernel pipeline.
// R7/R8 post-mortem: cooperative launch never executes here (R7 = stub
// output); R8's fallback was corrupted by my own reordering — prep wrote
// w2t at ws+600000 (inside h1's region) BEFORE adder1 overwrote it. w2t
// transpose must run after pool1 (h1 dead), as in R6. Ordering restored.
// Micro-opts this round (local, layout-preserving):
//   * bn_pool: float2 loads (even-aligned by construction).
//   * fc2_softmax: hid preloaded into 8 regs (1 read of hid per block).
// ---------------------------------------------------------------------------

#define B_N 128
#define EPSBN 1e-5f
#define NCOPY 16

// ---- adder1 + BN1 partials: x[128,1,28,28], w[20,1,5,5] -> h1[128,20,24,24]
// thread = (b,o,oh,owc in {0,1,2}) computing an 8-wide chunk of the ow row.
__global__ __launch_bounds__(256) void adder1_bn_kernel(
    const float* __restrict__ x, const float* __restrict__ w1,
    float* __restrict__ out, float* __restrict__ sums) {  // sums[NCOPY*40]
  __shared__ float csum[40];
  if (threadIdx.x < 40) csum[threadIdx.x] = 0.f;
  __syncthreads();
  int idx = blockIdx.x * 256 + threadIdx.x;   // 184320 = 720*256
  int owc = idx % 3; int t = idx / 3;
  int oh  = t % 24;  t /= 24;
  int o   = t % 20;  int b = t / 20;
  const float* xb = x + b * 784;
  const float* wb = w1 + o * 25;
  float acc[8];
#pragma unroll
  for (int i = 0; i < 8; ++i) acc[i] = 0.f;
#pragma unroll
  for (int kh = 0; kh < 5; ++kh) {
    float xr[12];
    const float4* xp = (const float4*)(xb + (oh + kh) * 28 + owc * 8);
#pragma unroll
    for (int i = 0; i < 3; ++i) {
      float4 v = xp[i];
      xr[4*i] = v.x; xr[4*i+1] = v.y; xr[4*i+2] = v.z; xr[4*i+3] = v.w;
    }
    float wr[5];
#pragma unroll
    for (int i = 0; i < 5; ++i) wr[i] = wb[kh * 5 + i];
#pragma unroll
    for (int ow = 0; ow < 8; ++ow)
#pragma unroll
      for (int kw = 0; kw < 5; ++kw)
        acc[ow] += fabsf(xr[ow + kw] - wr[kw]);
  }
  float* op = out + (((size_t)b * 20 + o) * 24 + oh) * 24 + owc * 8;
  float4 s0 = { -acc[0], -acc[1], -acc[2], -acc[3] };
  float4 s1 = { -acc[4], -acc[5], -acc[6], -acc[7] };
  *(float4*)(op)     = s0;
  *(float4*)(op + 4) = s1;
  float s = 0.f, s2 = 0.f;
#pragma unroll
  for (int i = 0; i < 8; ++i) { s -= acc[i]; s2 += acc[i] * acc[i]; }
  atomicAdd(&csum[o * 2],     s);
  atomicAdd(&csum[o * 2 + 1], s2);
  __syncthreads();
  if (threadIdx.x < 40) {
    float v = csum[threadIdx.x];
    if (v != 0.f)
      atomicAdd(&sums[(blockIdx.x & (NCOPY - 1)) * 40 + threadIdx.x], v);
  }
}

// ---- BN finalize (16-copy sum) + apply + 2x2 maxpool -----------------------
__global__ __launch_bounds__(256) void bn_pool_kernel(
    const float* __restrict__ h, const float* __restrict__ sums, int stride,
    const float* __restrict__ gamma, const float* __restrict__ beta,
    float* __restrict__ out, int C, int Hin, int Hout, float inv_n) {
  int idx = blockIdx.x * 256 + threadIdx.x;
  int pw = idx % Hout; int t = idx / Hout;
  int ph = t % Hout;   t /= Hout;
  int c  = t % C;      int b = t / C;
  float sm = 0.f, s2 = 0.f;
#pragma unroll
  for (int cp = 0; cp < NCOPY; ++cp) {
    sm += sums[cp * stride + 2 * c];
    s2 += sums[cp * stride + 2 * c + 1];
  }
  float mean = sm * inv_n;
  float var  = s2 * inv_n - mean * mean;
  float sc   = gamma[c] * rsqrtf(var + EPSBN);
  float bi   = beta[c] - mean * sc;
  const float* hp = h + ((b * C + c) * Hin + 2 * ph) * Hin + 2 * pw;
  float2 r0 = *(const float2*)(hp);         // even-aligned: 2*pw, Hin even
  float2 r1 = *(const float2*)(hp + Hin);
  float v0 = fmaf(sc, r0.x, bi);
  float v1 = fmaf(sc, r0.y, bi);
  float v2 = fmaf(sc, r1.x, bi);
  float v3 = fmaf(sc, r1.y, bi);
  out[idx] = fmaxf(fmaxf(v0, v1), fmaxf(v2, v3));
}

// ---- BN finalize + apply + 2x2 maxpool, TRANSPOSED out: featT[k][b] --------
__global__ __launch_bounds__(256) void bn_pool_t_kernel(
    const float* __restrict__ h, const float* __restrict__ sums,
    const float* __restrict__ gamma, const float* __restrict__ beta,
    float* __restrict__ outT, float inv_n) {   // h:[128,50,8,8] -> outT[800][128]
  int idx = blockIdx.x * 256 + threadIdx.x;    // 102400 = 400*256
  int pw = idx % 4; int t = idx / 4;
  int ph = t % 4;   t /= 4;
  int c  = t % 50;  int b = t / 50;
  float sm = 0.f, s2 = 0.f;
#pragma unroll
  for (int cp = 0; cp < NCOPY; ++cp) {
    sm += sums[cp * 100 + 2 * c];
    s2 += sums[cp * 100 + 2 * c + 1];
  }
  float mean = sm * inv_n;
  float var  = s2 * inv_n - mean * mean;
  float sc   = gamma[c] * rsqrtf(var + EPSBN);
  float bi   = beta[c] - mean * sc;
  const float* hp = h + ((b * 50 + c) * 8 + 2 * ph) * 8 + 2 * pw;
  float2 r0 = *(const float2*)(hp);
  float2 r1 = *(const float2*)(hp + 8);
  float v0 = fmaf(sc, r0.x, bi);
  float v1 = fmaf(sc, r0.y, bi);
  float v2 = fmaf(sc, r1.x, bi);
  float v3 = fmaf(sc, r1.y, bi);
  int k = (c * 16 + ph * 4 + pw);
  outT[k * 128 + b] = fmaxf(fmaxf(v0, v1), fmaxf(v2, v3));
}

// ---- w2 transpose: w2[50,20,5,5] -> w2t[c][k][o] = [20][25][64] ------------
// MUST run after bn_pool (h1 dead): w2t lives inside the dead-h1 region.
__global__ __launch_bounds__(256) void w2t_prep_kernel(
    const float* __restrict__ w2, float* __restrict__ w2t) {
  int idx = blockIdx.x * 256 + threadIdx.x;   // 32000 = 125*256
  int o = idx & 63;
  int t = idx >> 6;        // c*25 + k
  int k = t % 25, c = t / 25;
  w2t[idx] = (o < 50) ? w2[o * 500 + c * 25 + k] : 0.f;
}

// ---- adder2 + BN2 partials, LDS-staged: h1p[128,20,12,12] -> h2[128,50,8,8]
__global__ __launch_bounds__(256) void adder2_bn_kernel(
    const float* __restrict__ h, const float* __restrict__ w2t,
    float* __restrict__ out, float* __restrict__ sums) {  // sums[NCOPY*100]
  __shared__ float lh[1440];    // [c][6 rows][12]
  __shared__ float csum[100];
  if (threadIdx.x < 100) csum[threadIdx.x] = 0.f;
  const int oq = blockIdx.x & 3;
  const int b  = blockIdx.x >> 2;   // 512 blocks = 128 b * 4 oq
  {
    const float* hb = h + (size_t)b * 2880 + 2 * oq * 12;
    float2* dst = (float2*)lh;
    for (int j = threadIdx.x; j < 720; j += 256) {
      int c = j / 36, rem = j - c * 36;
      dst[j] = ((const float2*)(hb + c * 144))[rem];
    }
  }
  __syncthreads();
  const int o   = threadIdx.x >> 2;
  const int q   = threadIdx.x & 3;
  const int ohl = q >> 1;
  const int owh = q & 1;
  if (o < 50) {
    float acc[4];
#pragma unroll
    for (int i = 0; i < 4; ++i) acc[i] = 0.f;
    for (int c = 0; c < 20; ++c) {
      const float* lc = lh + c * 72 + owh * 4;
      const float* wc = w2t + c * 1600 + o;
#pragma unroll
      for (int kh = 0; kh < 5; ++kh) {
        float hr[8];
        const float* lp = lc + (ohl + kh) * 12;
        *(float4*)(hr)     = *(const float4*)(lp);
        *(float4*)(hr + 4) = *(const float4*)(lp + 4);
        float wr[5];
#pragma unroll
        for (int i = 0; i < 5; ++i) wr[i] = wc[(kh * 5 + i) * 64];
#pragma unroll
        for (int ow = 0; ow < 4; ++ow)
#pragma unroll
          for (int kw = 0; kw < 5; ++kw)
            acc[ow] += fabsf(hr[ow + kw] - wr[kw]);
      }
    }
    const int oh = 2 * oq + ohl;
    float4 st = { -acc[0], -acc[1], -acc[2], -acc[3] };
    *(float4*)(out + (((size_t)b * 50 + o) * 8 + oh) * 8 + owh * 4) = st;
    float s = 0.f, s2 = 0.f;
#pragma unroll
    for (int i = 0; i < 4; ++i) { s -= acc[i]; s2 += acc[i] * acc[i]; }
    atomicAdd(&csum[o * 2],     s);
    atomicAdd(&csum[o * 2 + 1], s2);
  }
  __syncthreads();
  if (threadIdx.x < 100)
    atomicAdd(&sums[(blockIdx.x & (NCOPY - 1)) * 100 + threadIdx.x],
              csum[threadIdx.x]);
}

// ---- fc1 + relu: featT[800][128] x w[500,800] -> hid[128][512] -------------
__global__ __launch_bounds__(256) void fc1_kernel(
    const float* __restrict__ featT, const float* __restrict__ w1,
    const float* __restrict__ b1, float* __restrict__ hid) {
  const int j = blockIdx.x;
  const int b = threadIdx.x & 127;
  const int khalf = threadIdx.x >> 7;
  const float* wr = w1 + j * 800;
  const float* fb = featT + b;
  float a0 = 0.f, a1 = 0.f, a2 = 0.f, a3 = 0.f;
  int k0 = khalf * 400;
  for (int k = k0; k < k0 + 400; k += 4) {
    float4 w4 = *(const float4*)(wr + k);   // wave-uniform
    a0 = fmaf(fb[(k    ) * 128], w4.x, a0);
    a1 = fmaf(fb[(k + 1) * 128], w4.y, a1);
    a2 = fmaf(fb[(k + 2) * 128], w4.z, a2);
    a3 = fmaf(fb[(k + 3) * 128], w4.w, a3);
  }
  __shared__ float part[256];
  part[threadIdx.x] = (a0 + a1) + (a2 + a3);
  __syncthreads();
  if (threadIdx.x < 128)
    hid[b * 512 + j] =
        fmaxf(b1[j] + part[threadIdx.x] + part[threadIdx.x + 128], 0.f);
}

// ---- fc2 + bias + softmax: hid[128][512] x w[10,500] -> out[128][10] -------
// hid preloaded once into 8 regs (k<500 guard; hid[500..512) is poison).
__global__ __launch_bounds__(64) void fc2_softmax_kernel(
    const float* __restrict__ hid, const float* __restrict__ w2,
    const float* __restrict__ b2, float* __restrict__ out) {
  const int b = blockIdx.x, lane = threadIdx.x;
  const float* hb = hid + b * 512;
  __shared__ float logit[16];
  float hv[8];
#pragma unroll
  for (int i = 0; i < 8; ++i) {
    int k = lane + 64 * i;
    hv[i] = (k < 500) ? hb[k] : 0.f;
  }
  for (int j = 0; j < 10; ++j) {
    const float* wr = w2 + j * 500;
    float acc = 0.f;
#pragma unroll
    for (int i = 0; i < 8; ++i) {
      int k = lane + 64 * i;
      float w = (k < 500) ? wr[k] : 0.f;
      acc = fmaf(hv[i], w, acc);
    }
#pragma unroll
    for (int off = 32; off > 0; off >>= 1) acc += __shfl_down(acc, off);
    if (lane == 0) logit[j] = acc + b2[j];
  }
  __syncthreads();
  if (lane == 0) {
    float m = logit[0];
    for (int j = 1; j < 10; ++j) m = fmaxf(m, logit[j]);
    float s = 0.f, e[10];
    for (int j = 0; j < 10; ++j) { e[j] = __expf(logit[j] - m); s += e[j]; }
    float inv = 1.f / s;
    for (int j = 0; j < 10; ++j) out[b * 10 + j] = e[j] * inv;
  }
}

extern "C" void kernel_launch(void* const* d_in, const int* in_sizes, int n_in,
                              void* d_out, int out_size, void* d_ws, size_t ws_size,
                              hipStream_t stream) {
  const float* x   = (const float*)d_in[0];   // [128,1,28,28]
  const float* w1  = (const float*)d_in[1];   // [20,1,5,5]
  const float* g1  = (const float*)d_in[2];   // [20]
  const float* be1 = (const float*)d_in[3];   // [20]
  const float* w2  = (const float*)d_in[4];   // [50,20,5,5]
  const float* g2  = (const float*)d_in[5];   // [50]
  const float* be2 = (const float*)d_in[6];   // [50]
  const float* fw1 = (const float*)d_in[7];   // [500,800]
  const float* fb1 = (const float*)d_in[8];   // [500]
  const float* fw2 = (const float*)d_in[9];   // [10,500]
  const float* fb2 = (const float*)d_in[10];  // [10]
  float* out = (float*)d_out;

  // workspace layout (floats). Lifetimes:
  //   h1 [0,1474560): written by adder1, dead after bn_pool.
  //   h1p [1474560,1843200): written by bn_pool, dead after adder2 staging.
  //   h2/featT/hid/w2t all live inside the dead-h1 region (written only
  //   after bn_pool completes). w2t_prep MUST follow bn_pool (R8 bug).
  float* ws    = (float*)d_ws;
  float* h1    = ws;               // [0, 1474560)
  float* h1p   = ws + 1474560;     // [1474560, 1843200)
  float* h2    = ws;               // reuse dead h1: [0, 409600)
  float* featT = ws + 409600;      // 800*128
  float* hid   = ws + 512000;      // 128*512
  float* w2t   = ws + 600000;      // 20*25*64
  float* sums1 = ws + 1843200;     // NCOPY*40
  float* sums2 = sums1 + NCOPY*40; // NCOPY*100

  hipMemsetAsync(sums1, 0, NCOPY * 140 * sizeof(float), stream);

  adder1_bn_kernel<<<720, 256, 0, stream>>>(x, w1, h1, sums1);
  bn_pool_kernel<<<1440, 256, 0, stream>>>(h1, sums1, 40, g1, be1, h1p,
                                           20, 24, 12, 1.f / (B_N * 576));
  w2t_prep_kernel<<<125, 256, 0, stream>>>(w2, w2t);   // after bn_pool!
  adder2_bn_kernel<<<512, 256, 0, stream>>>(h1p, w2t, h2, sums2);
  bn_pool_t_kernel<<<400, 256, 0, stream>>>(h2, sums2, g2, be2, featT,
                                            1.f / (B_N * 64));
  fc1_kernel<<<500, 256, 0, stream>>>(featT, fw1, fb1, hid);
  fc2_softmax_kernel<<<128, 64, 0, stream>>>(hid, fw2, fb2, out);
}

// Round 10
// 141.809 us; speedup vs baseline: 1.5005x; 1.0403x over previous
//
#include <hip/hip_runtime.h>
#include <hip/hip_bf16.h>
#include <math.h>

// ---------------------------------------------------------------------------
// AdderNet LeNet forward. R10: dispatch-count round (8 -> 6).
//  * prep_kernel: zero BN accumulators + w2t transpose in one launch, FIRST.
//    Safe now: ws is ~268MB (fill WRITE_SIZE evidence), so every buffer gets
//    a disjoint offset — no h1-region reuse, no lifetime aliasing (R8 bug
//    class eliminated structurally).
//  * bn_pool (BN1 finalize + 2x2 pool) fused INTO adder2's LDS staging:
//    block computes scale/bias from sums1 once, then stages pooled h1
//    directly. Kills the 1440-block pool1 kernel + h1p roundtrip.
//  * pool_t / fc1 / fc2 unchanged from R9 (proven).
// ---------------------------------------------------------------------------

#define B_N 128
#define EPSBN 1e-5f
#define NCOPY 16

// ---- prep: w2t[c][k][o(64)] transpose + zero sums --------------------------
__global__ __launch_bounds__(256) void prep_kernel(
    const float* __restrict__ w2, float* __restrict__ w2t,
    float* __restrict__ sums) {
  int idx = blockIdx.x * 256 + threadIdx.x;   // 134*256 = 34304
  if (idx < 32000) {
    int o = idx & 63, t = idx >> 6, k = t % 25, c = t / 25;
    w2t[idx] = (o < 50) ? w2[o * 500 + c * 25 + k] : 0.f;
  } else {
    int j = idx - 32000;
    if (j < NCOPY * 140) sums[j] = 0.f;
  }
}

// ---- adder1 + BN1 partials: x[128,1,28,28], w[20,1,5,5] -> h1[128,20,24,24]
__global__ __launch_bounds__(256) void adder1_bn_kernel(
    const float* __restrict__ x, const float* __restrict__ w1,
    float* __restrict__ out, float* __restrict__ sums) {  // sums[NCOPY*40]
  __shared__ float csum[40];
  if (threadIdx.x < 40) csum[threadIdx.x] = 0.f;
  __syncthreads();
  int idx = blockIdx.x * 256 + threadIdx.x;   // 184320 = 720*256
  int owc = idx % 3; int t = idx / 3;
  int oh  = t % 24;  t /= 24;
  int o   = t % 20;  int b = t / 20;
  const float* xb = x + b * 784;
  const float* wb = w1 + o * 25;
  float acc[8];
#pragma unroll
  for (int i = 0; i < 8; ++i) acc[i] = 0.f;
#pragma unroll
  for (int kh = 0; kh < 5; ++kh) {
    float xr[12];
    const float4* xp = (const float4*)(xb + (oh + kh) * 28 + owc * 8);
#pragma unroll
    for (int i = 0; i < 3; ++i) {
      float4 v = xp[i];
      xr[4*i] = v.x; xr[4*i+1] = v.y; xr[4*i+2] = v.z; xr[4*i+3] = v.w;
    }
    float wr[5];
#pragma unroll
    for (int i = 0; i < 5; ++i) wr[i] = wb[kh * 5 + i];
#pragma unroll
    for (int ow = 0; ow < 8; ++ow)
#pragma unroll
      for (int kw = 0; kw < 5; ++kw)
        acc[ow] += fabsf(xr[ow + kw] - wr[kw]);
  }
  float* op = out + (((size_t)b * 20 + o) * 24 + oh) * 24 + owc * 8;
  float4 s0 = { -acc[0], -acc[1], -acc[2], -acc[3] };
  float4 s1 = { -acc[4], -acc[5], -acc[6], -acc[7] };
  *(float4*)(op)     = s0;
  *(float4*)(op + 4) = s1;
  float s = 0.f, s2 = 0.f;
#pragma unroll
  for (int i = 0; i < 8; ++i) { s -= acc[i]; s2 += acc[i] * acc[i]; }
  atomicAdd(&csum[o * 2],     s);
  atomicAdd(&csum[o * 2 + 1], s2);
  __syncthreads();
  if (threadIdx.x < 40) {
    float v = csum[threadIdx.x];
    if (v != 0.f)
      atomicAdd(&sums[(blockIdx.x & (NCOPY - 1)) * 40 + threadIdx.x], v);
  }
}

// ---- adder2 + fused BN1-finalize/pool staging + BN2 partials ---------------
// block=(b,oq): BN1 scale/bias from sums1 (threads 0-19), stage pooled h1
// rows [2oq,2oq+6) x 20c into LDS, then 4-wide quad compute as in R6/R9.
__global__ __launch_bounds__(256) void adder2_bn_kernel(
    const float* __restrict__ h1, const float* __restrict__ sums1,
    const float* __restrict__ g1, const float* __restrict__ be1,
    const float* __restrict__ w2t,
    float* __restrict__ out, float* __restrict__ sums2) { // sums2[NCOPY*100]
  __shared__ float lh[1440];    // [c][6 rows][12]
  __shared__ float sb[40];      // (scale,bias) per channel
  __shared__ float csum[100];
  const int tid = threadIdx.x;
  if (tid < 100) csum[tid] = 0.f;
  if (tid < 20) {
    float sm = 0.f, s2 = 0.f;
#pragma unroll
    for (int cp = 0; cp < NCOPY; ++cp) {
      sm += sums1[cp * 40 + 2 * tid];
      s2 += sums1[cp * 40 + 2 * tid + 1];
    }
    const float inv_n = 1.f / (B_N * 576);
    float mean = sm * inv_n;
    float var  = s2 * inv_n - mean * mean;
    float sc   = g1[tid] * rsqrtf(var + EPSBN);
    sb[2 * tid]     = sc;
    sb[2 * tid + 1] = be1[tid] - mean * sc;
  }
  __syncthreads();

  const int oq = blockIdx.x & 3;
  const int b  = blockIdx.x >> 2;   // 512 blocks = 128 b * 4 oq

  // stage: lh[c][r][col] = BN+pool of h1[b][c][4oq+2r .. +1][2col .. +1]
  {
    const float* hb = h1 + (size_t)b * 11520;   // 20*24*24
    for (int j = tid; j < 1440; j += 256) {
      int c = j / 72, rem = j - c * 72;
      int r = rem / 12, col = rem - r * 12;
      const float* hp = hb + (c * 24 + (4 * oq + 2 * r)) * 24 + 2 * col;
      float2 r0 = *(const float2*)(hp);
      float2 r1 = *(const float2*)(hp + 24);
      float sc = sb[2 * c], bi = sb[2 * c + 1];
      float v0 = fmaf(sc, r0.x, bi);
      float v1 = fmaf(sc, r0.y, bi);
      float v2 = fmaf(sc, r1.x, bi);
      float v3 = fmaf(sc, r1.y, bi);
      lh[j] = fmaxf(fmaxf(v0, v1), fmaxf(v2, v3));
    }
  }
  __syncthreads();

  const int o   = tid >> 2;
  const int q   = tid & 3;
  const int ohl = q >> 1;
  const int owh = q & 1;
  if (o < 50) {
    float acc[4];
#pragma unroll
    for (int i = 0; i < 4; ++i) acc[i] = 0.f;
    for (int c = 0; c < 20; ++c) {
      const float* lc = lh + c * 72 + owh * 4;
      const float* wc = w2t + c * 1600 + o;
#pragma unroll
      for (int kh = 0; kh < 5; ++kh) {
        float hr[8];
        const float* lp = lc + (ohl + kh) * 12;
        *(float4*)(hr)     = *(const float4*)(lp);
        *(float4*)(hr + 4) = *(const float4*)(lp + 4);
        float wr[5];
#pragma unroll
        for (int i = 0; i < 5; ++i) wr[i] = wc[(kh * 5 + i) * 64];
#pragma unroll
        for (int ow = 0; ow < 4; ++ow)
#pragma unroll
          for (int kw = 0; kw < 5; ++kw)
            acc[ow] += fabsf(hr[ow + kw] - wr[kw]);
      }
    }
    const int oh = 2 * oq + ohl;
    float4 st = { -acc[0], -acc[1], -acc[2], -acc[3] };
    *(float4*)(out + (((size_t)b * 50 + o) * 8 + oh) * 8 + owh * 4) = st;
    float s = 0.f, s2 = 0.f;
#pragma unroll
    for (int i = 0; i < 4; ++i) { s -= acc[i]; s2 += acc[i] * acc[i]; }
    atomicAdd(&csum[o * 2],     s);
    atomicAdd(&csum[o * 2 + 1], s2);
  }
  __syncthreads();
  if (tid < 100)
    atomicAdd(&sums2[(blockIdx.x & (NCOPY - 1)) * 100 + tid], csum[tid]);
}

// ---- BN2 finalize + apply + 2x2 maxpool, TRANSPOSED out: featT[k][b] -------
__global__ __launch_bounds__(256) void bn_pool_t_kernel(
    const float* __restrict__ h, const float* __restrict__ sums,
    const float* __restrict__ gamma, const float* __restrict__ beta,
    float* __restrict__ outT, float inv_n) {   // h:[128,50,8,8] -> outT[800][128]
  int idx = blockIdx.x * 256 + threadIdx.x;    // 102400 = 400*256
  int pw = idx % 4; int t = idx / 4;
  int ph = t % 4;   t /= 4;
  int c  = t % 50;  int b = t / 50;
  float sm = 0.f, s2 = 0.f;
#pragma unroll
  for (int cp = 0; cp < NCOPY; ++cp) {
    sm += sums[cp * 100 + 2 * c];
    s2 += sums[cp * 100 + 2 * c + 1];
  }
  float mean = sm * inv_n;
  float var  = s2 * inv_n - mean * mean;
  float sc   = gamma[c] * rsqrtf(var + EPSBN);
  float bi   = beta[c] - mean * sc;
  const float* hp = h + ((b * 50 + c) * 8 + 2 * ph) * 8 + 2 * pw;
  float2 r0 = *(const float2*)(hp);
  float2 r1 = *(const float2*)(hp + 8);
  float v0 = fmaf(sc, r0.x, bi);
  float v1 = fmaf(sc, r0.y, bi);
  float v2 = fmaf(sc, r1.x, bi);
  float v3 = fmaf(sc, r1.y, bi);
  int k = (c * 16 + ph * 4 + pw);
  outT[k * 128 + b] = fmaxf(fmaxf(v0, v1), fmaxf(v2, v3));
}

// ---- fc1 + relu: featT[800][128] x w[500,800] -> hid[128][512] -------------
__global__ __launch_bounds__(256) void fc1_kernel(
    const float* __restrict__ featT, const float* __restrict__ w1,
    const float* __restrict__ b1, float* __restrict__ hid) {
  const int j = blockIdx.x;
  const int b = threadIdx.x & 127;
  const int khalf = threadIdx.x >> 7;
  const float* wr = w1 + j * 800;
  const float* fb = featT + b;
  float a0 = 0.f, a1 = 0.f, a2 = 0.f, a3 = 0.f;
  int k0 = khalf * 400;
  for (int k = k0; k < k0 + 400; k += 4) {
    float4 w4 = *(const float4*)(wr + k);   // wave-uniform
    a0 = fmaf(fb[(k    ) * 128], w4.x, a0);
    a1 = fmaf(fb[(k + 1) * 128], w4.y, a1);
    a2 = fmaf(fb[(k + 2) * 128], w4.z, a2);
    a3 = fmaf(fb[(k + 3) * 128], w4.w, a3);
  }
  __shared__ float part[256];
  part[threadIdx.x] = (a0 + a1) + (a2 + a3);
  __syncthreads();
  if (threadIdx.x < 128)
    hid[b * 512 + j] =
        fmaxf(b1[j] + part[threadIdx.x] + part[threadIdx.x + 128], 0.f);
}

// ---- fc2 + bias + softmax: hid[128][512] x w[10,500] -> out[128][10] -------
__global__ __launch_bounds__(64) void fc2_softmax_kernel(
    const float* __restrict__ hid, const float* __restrict__ w2,
    const float* __restrict__ b2, float* __restrict__ out) {
  const int b = blockIdx.x, lane = threadIdx.x;
  const float* hb = hid + b * 512;
  __shared__ float logit[16];
  float hv[8];
#pragma unroll
  for (int i = 0; i < 8; ++i) {
    int k = lane + 64 * i;
    hv[i] = (k < 500) ? hb[k] : 0.f;
  }
  for (int j = 0; j < 10; ++j) {
    const float* wr = w2 + j * 500;
    float acc = 0.f;
#pragma unroll
    for (int i = 0; i < 8; ++i) {
      int k = lane + 64 * i;
      float w = (k < 500) ? wr[k] : 0.f;
      acc = fmaf(hv[i], w, acc);
    }
#pragma unroll
    for (int off = 32; off > 0; off >>= 1) acc += __shfl_down(acc, off);
    if (lane == 0) logit[j] = acc + b2[j];
  }
  __syncthreads();
  if (lane == 0) {
    float m = logit[0];
    for (int j = 1; j < 10; ++j) m = fmaxf(m, logit[j]);
    float s = 0.f, e[10];
    for (int j = 0; j < 10; ++j) { e[j] = __expf(logit[j] - m); s += e[j]; }
    float inv = 1.f / s;
    for (int j = 0; j < 10; ++j) out[b * 10 + j] = e[j] * inv;
  }
}

extern "C" void kernel_launch(void* const* d_in, const int* in_sizes, int n_in,
                              void* d_out, int out_size, void* d_ws, size_t ws_size,
                              hipStream_t stream) {
  const float* x   = (const float*)d_in[0];   // [128,1,28,28]
  const float* w1  = (const float*)d_in[1];   // [20,1,5,5]
  const float* g1  = (const float*)d_in[2];   // [20]
  const float* be1 = (const float*)d_in[3];   // [20]
  const float* w2  = (const float*)d_in[4];   // [50,20,5,5]
  const float* g2  = (const float*)d_in[5];   // [50]
  const float* be2 = (const float*)d_in[6];   // [50]
  const float* fw1 = (const float*)d_in[7];   // [500,800]
  const float* fb1 = (const float*)d_in[8];   // [500]
  const float* fw2 = (const float*)d_in[9];   // [10,500]
  const float* fb2 = (const float*)d_in[10];  // [10]
  float* out = (float*)d_out;

  // workspace layout (floats) — ALL DISJOINT (ws is ~268MB; no reuse games).
  float* ws    = (float*)d_ws;
  float* h1    = ws;               // [0, 1474560)         128*20*24*24
  float* sums1 = ws + 1843200;     // NCOPY*40   = 640
  float* sums2 = ws + 1843840;     // NCOPY*100  = 1600
  float* w2t   = ws + 1845504;     // 32000
  float* h2    = ws + 1900000;     // 409600     128*50*8*8
  float* featT = ws + 2310000;     // 102400     800*128
  float* hid   = ws + 2420000;     // 65536      128*512

  prep_kernel<<<134, 256, 0, stream>>>(w2, w2t, sums1);  // zeros sums1+sums2
  adder1_bn_kernel<<<720, 256, 0, stream>>>(x, w1, h1, sums1);
  adder2_bn_kernel<<<512, 256, 0, stream>>>(h1, sums1, g1, be1, w2t, h2, sums2);
  bn_pool_t_kernel<<<400, 256, 0, stream>>>(h2, sums2, g2, be2, featT,
                                            1.f / (B_N * 64));
  fc1_kernel<<<500, 256, 0, stream>>>(featT, fw1, fb1, hid);
  fc2_softmax_kernel<<<128, 64, 0, stream>>>(hid, fw2, fb2, out);
}